// Round 15
// baseline (658.805 us; speedup 1.0000x reference)
//
#include <hip/hip_runtime.h>

// ---------------- constants ----------------
#define S_LEN 2048
#define NH 32
#define NKV 8
#define HD 128
#define DMODEL 4096
#define MROWS 4096   // B*S
#define QKVN 6144    // 4096 q + 1024 k + 1024 v output cols

typedef short s16x8 __attribute__((ext_vector_type(8)));
typedef float fx4 __attribute__((ext_vector_type(4)));

__device__ __forceinline__ unsigned short f2bf(float f) {
  unsigned int u = __float_as_uint(f);
  u += 0x7fffu + ((u >> 16) & 1u);   // round-to-nearest-even
  return (unsigned short)(u >> 16);
}
__device__ __forceinline__ float bf2f(unsigned short h) {
  return __uint_as_float(((unsigned int)h) << 16);
}

#define GLDS16(gp, lp)                                                        \
  __builtin_amdgcn_global_load_lds(                                           \
      (const __attribute__((address_space(1))) void*)(gp),                    \
      (__attribute__((address_space(3))) void*)(lp), 16, 0, 0)

#define MFMA16(a, b, c) __builtin_amdgcn_mfma_f32_16x16x32_bf16((a), (b), (c), 0, 0, 0)

// ---------------- fused f32 -> bf16 casts, 8 floats/thread (R13-verified) ----------------
__global__ __launch_bounds__(256) void cast_all_k(const float* __restrict__ hs,
                                                  const float* __restrict__ Wq,
                                                  const float* __restrict__ Wk,
                                                  const float* __restrict__ Wv,
                                                  const float* __restrict__ Wo,
                                                  unsigned short* __restrict__ hsb,
                                                  unsigned short* __restrict__ wqkvb,
                                                  unsigned short* __restrict__ wob) {
  int i = blockIdx.x * 256 + threadIdx.x;   // float8 index
  const float* src;
  unsigned short* dst;
  int off;
  if (i < 2097152)      { src = hs; dst = hsb;               off = 0; }
  else if (i < 4194304) { src = Wq; dst = wqkvb;             off = 2097152; }
  else if (i < 4718592) { src = Wk; dst = wqkvb + 16777216;  off = 4194304; }
  else if (i < 5242880) { src = Wv; dst = wqkvb + 20971520;  off = 4718592; }
  else                  { src = Wo; dst = wob;               off = 5242880; }
  int j = i - off;
  float4 v0 = *(const float4*)(src + (size_t)j * 8);
  float4 v1 = *(const float4*)(src + (size_t)j * 8 + 4);
  s16x8 o;
  o[0] = (short)f2bf(v0.x); o[1] = (short)f2bf(v0.y);
  o[2] = (short)f2bf(v0.z); o[3] = (short)f2bf(v0.w);
  o[4] = (short)f2bf(v1.x); o[5] = (short)f2bf(v1.y);
  o[6] = (short)f2bf(v1.z); o[7] = (short)f2bf(v1.w);
  *(s16x8*)(dst + (size_t)j * 8) = o;
}

// ---------------- RoPE cos/sin table: tab[s*64+d2] = (cos, sin) ----------------
__global__ __launch_bounds__(256) void rope_tab_k(const float* __restrict__ freqs,
                                                  const int* __restrict__ pos,
                                                  float2* __restrict__ tab) {
  int i = blockIdx.x * 256 + threadIdx.x;  // S*64 = 131072
  int s = i >> 6, d = i & 63;
  float ang = freqs[((size_t)(pos[0] + s) << 6) + d];
  float sv, cv;
  sincosf(ang, &sv, &cv);
  tab[i] = make_float2(cv, sv);
}

// ---------------- 256x256 8-phase bf16 GEMM (R7-verified) + ldc + fused RoPE ----------------
// ropemode: 0 = none (O-proj), 1 = rope all cols (Q-proj), 2 = rope tiles tn<4
// only (KV-proj: K cols 0..1023; tn is block-uniform). Rope applied in f32 on
// the accumulator before f2bf: feature pairs sit in adjacent lanes (col =
// base + cn), so partner value comes from __shfl_xor(v,1).
__global__ __launch_bounds__(512, 2) void gemm256(const unsigned short* __restrict__ A,
                                                  const unsigned short* __restrict__ Bt,
                                                  float* __restrict__ Cf,
                                                  unsigned short* __restrict__ Cb,
                                                  const float2* __restrict__ tab,
                                                  int M, int N, int K, int ldc,
                                                  int ropemode, int bf16out) {
  __shared__ unsigned short Abuf[2][16384];  // [2][256 rows][64 cols]
  __shared__ unsigned short Bbuf[2][16384];
  const int tid = threadIdx.x;
  const int lane = tid & 63;
  const int w = tid >> 6;
  const int wm = w >> 2;   // 0..1
  const int wn = w & 3;    // 0..3

  const int nm = M >> 8;
  const int nn = N >> 8;
  const int rh = nm >> 1;              // rectangle height (tiles)
  const int rw = nn >> 2;              // rectangle width (tiles)
  const int xcd = blockIdx.x & 7;
  const int l = blockIdx.x >> 3;       // per-XCD sequence
  const int tm = (xcd >> 2) * rh + (l % rh);
  const int tn = (xcd & 3) * rw + (l / rh);

  const int opr = lane & 15;
  const int opk2 = (lane >> 4) << 4;   // byte offset {0,16,32,48}
  const int NT = K >> 6;

  const unsigned short* Agbase = A + (size_t)(tm * 256) * K;
  const unsigned short* Bgbase = Bt + (size_t)(tn * 256) * K;
  const int abase = wm * 16384 + wn * 4096;
  const int bbase = (wn >> 1) * 16384 + (wm * 2 + (wn & 1)) * 4096;

  auto stageA = [&](int bsel, int kt) {
#pragma unroll
    for (int r = 0; r < 4; ++r) {
      const int d = abase + r * 1024 + lane * 16;
      const int row = d >> 7;
      const int u = (d & 127) ^ ((row & 7) << 4);
      GLDS16(Agbase + (size_t)row * K + kt * 64 + (u >> 1), (char*)&Abuf[bsel][0] + d);
    }
  };
  auto stageB = [&](int bsel, int kt) {
#pragma unroll
    for (int r = 0; r < 4; ++r) {
      const int d = bbase + r * 1024 + lane * 16;
      const int row = d >> 7;
      const int u = (d & 127) ^ ((row & 7) << 4);
      GLDS16(Bgbase + (size_t)row * K + kt * 64 + (u >> 1), (char*)&Bbuf[bsel][0] + d);
    }
  };

  fx4 acc[8][4] = {};

  stageA(0, 0); stageB(0, 0);
  stageA(1, 1); stageB(1, 1);
  asm volatile("s_waitcnt vmcnt(8)" ::: "memory");
  __builtin_amdgcn_s_barrier();

#define PH_SYNC()                                            \
  do {                                                       \
    __builtin_amdgcn_s_barrier();                            \
    asm volatile("s_waitcnt lgkmcnt(0)" ::: "memory");       \
    __builtin_amdgcn_sched_barrier(0);                       \
  } while (0)

#pragma unroll 1
  for (int t = 0; t < NT; ++t) {
    const int cur = t & 1;
    const unsigned short* Abc = Abuf[cur];
    const unsigned short* Bbc = Bbuf[cur];
    const int kt2 = (t + 2) & (NT - 1);
    s16x8 a0[8], a1[8], b0[4], b1[4];

#pragma unroll
    for (int i = 0; i < 8; ++i) {
      const int row = wm * 128 + i * 16 + opr;
      a0[i] = *(const s16x8*)((const char*)Abc + row * 128 + (opk2 ^ ((row & 7) << 4)));
    }
#pragma unroll
    for (int j = 0; j < 4; ++j) {
      const int row = wn * 64 + j * 16 + opr;
      b0[j] = *(const s16x8*)((const char*)Bbc + row * 128 + (opk2 ^ ((row & 7) << 4)));
    }
    PH_SYNC();
    __builtin_amdgcn_s_setprio(1);
#pragma unroll
    for (int i = 0; i < 4; ++i)
#pragma unroll
      for (int j = 0; j < 4; ++j) acc[i][j] = MFMA16(a0[i], b0[j], acc[i][j]);
    __builtin_amdgcn_s_setprio(0);
    __builtin_amdgcn_s_barrier();

#pragma unroll
    for (int i = 0; i < 8; ++i) {
      const int row = wm * 128 + i * 16 + opr;
      a1[i] = *(const s16x8*)((const char*)Abc + row * 128 + ((64 + opk2) ^ ((row & 7) << 4)));
    }
    PH_SYNC();
    __builtin_amdgcn_s_setprio(1);
#pragma unroll
    for (int i = 4; i < 8; ++i)
#pragma unroll
      for (int j = 0; j < 4; ++j) acc[i][j] = MFMA16(a0[i], b0[j], acc[i][j]);
    __builtin_amdgcn_s_setprio(0);
    __builtin_amdgcn_s_barrier();

#pragma unroll
    for (int j = 0; j < 4; ++j) {
      const int row = wn * 64 + j * 16 + opr;
      b1[j] = *(const s16x8*)((const char*)Bbc + row * 128 + ((64 + opk2) ^ ((row & 7) << 4)));
    }
    stageA(cur, kt2);
    PH_SYNC();
    __builtin_amdgcn_s_setprio(1);
#pragma unroll
    for (int i = 0; i < 4; ++i)
#pragma unroll
      for (int j = 0; j < 4; ++j) acc[i][j] = MFMA16(a1[i], b1[j], acc[i][j]);
    __builtin_amdgcn_s_setprio(0);
    __builtin_amdgcn_s_barrier();

    stageB(cur, kt2);
    __builtin_amdgcn_s_barrier();
    __builtin_amdgcn_s_setprio(1);
#pragma unroll
    for (int i = 4; i < 8; ++i)
#pragma unroll
      for (int j = 0; j < 4; ++j) acc[i][j] = MFMA16(a1[i], b1[j], acc[i][j]);
    __builtin_amdgcn_s_setprio(0);
    asm volatile("s_waitcnt vmcnt(8)" ::: "memory");
    __builtin_amdgcn_s_barrier();
  }
#undef PH_SYNC

  const int cm = (lane >> 4) << 2;
  const int cn = lane & 15;
  const bool do_rope = (ropemode == 1) || (ropemode == 2 && tn < 4);
#pragma unroll
  for (int i = 0; i < 8; ++i)
#pragma unroll
    for (int j = 0; j < 4; ++j) {
      const int row = tm * 256 + wm * 128 + i * 16 + cm;
      const int col = tn * 256 + wn * 64 + j * 16 + cn;
      const int d2 = (col & 127) >> 1;
#pragma unroll
      for (int r = 0; r < 4; ++r) {
        float v = acc[i][j][r];
        float vp = __shfl_xor(v, 1);   // partner feature (lane^1), uniform exec
        if (do_rope) {
          int s = (row + r) & (S_LEN - 1);
          float2 cs = tab[(s << 6) + d2];
          v = ((cn & 1) == 0) ? (v * cs.x - vp * cs.y)   // x1' = x1 c - x2 s
                              : (vp * cs.y + v * cs.x);  // x2' = x1 s + x2 c
        }
        if (bf16out) Cb[(size_t)(row + r) * ldc + col] = f2bf(v);
        else         Cf[(size_t)(row + r) * ldc + col] = v;
      }
    }
}

// ---------------- bf16 transpose: out[C][R] = in[R][C]^T (in rows strided) ----------------
__global__ __launch_bounds__(256) void transpose_k(const unsigned short* __restrict__ in,
                                                   unsigned short* __restrict__ out,
                                                   int R, int C, int istride) {
  __shared__ unsigned short T[64][68];
  const int tid = threadIdx.x;
  const int nbc = C >> 6;
  const int br = blockIdx.x / nbc;
  const int bc = blockIdx.x % nbc;
  const int r0 = br << 6, c0 = bc << 6;
#pragma unroll
  for (int i = 0; i < 4; ++i) {
    int row = i * 16 + (tid >> 4);
    int col = (tid & 15) << 2;
    *(ushort4*)&T[row][col] = *(const ushort4*)(in + (size_t)(r0 + row) * istride + c0 + col);
  }
  __syncthreads();
#pragma unroll
  for (int i = 0; i < 4; ++i) {
    int row = i * 16 + (tid >> 4);
    int col = (tid & 15) << 2;
    ushort4 v;
    v.x = T[col + 0][row]; v.y = T[col + 1][row];
    v.z = T[col + 2][row]; v.w = T[col + 3][row];
    *(ushort4*)(out + (size_t)(c0 + row) * R + r0 + col) = v;
  }
}

// ---------------- MFMA flash attention — R13-verified geometry + packed P-stores ----------------
// Only change vs R13: the 32 scalar ds_write_b16 P-stores per wave-tile are
// packed into 8 ushort4 (ds_write_b64) stores — same values (f2bf kept), same
// addresses, bit-identical output; 2-way bank conflict instead of 4-way.
__global__ __launch_bounds__(256, 2) void attn_mfma(const unsigned short* __restrict__ qkv,
                                                    const unsigned short* __restrict__ vtb,
                                                    unsigned short* __restrict__ aob) {
  __shared__ alignas(16) unsigned short Ks[64 * 128];    // 16 KB (swizzled)
  __shared__ alignas(16) unsigned short Vts[128 * 64];   // 16 KB (swizzled)
  __shared__ alignas(16) unsigned short Ps[4][32 * 72];  // 18 KB
  const int tid = threadIdx.x;
  const int lane = tid & 63;
  const int w = tid >> 6;
  const int lg = (blockIdx.x & 7) * 128 + (blockIdx.x >> 3);  // grid = 1024
  const int qc = lg & 15;            // 16 q-chunks of 128 rows
  const int hsub = (lg >> 4) & 3;
  const int kvi = (lg >> 6) & 7;
  const int b = lg >> 9;
  const int h = kvi * 4 + hsub;

  const int opr = lane & 15;         // operand row within 16
  const int g = lane >> 4;           // k-subblock 0..3
  const int ak = g * 8;              // operand k offset (shorts)
  const int opk2 = g * 16;           // operand k offset (bytes)
  const int cm = g * 4;              // C/D row base
  const int cn = opr;                // C/D col

  const int qrow0 = b * S_LEN + qc * 128 + w * 32;
  unsigned short* Pw = Ps[w];

  // ---- Q b-frags hoisted once from global ----
  s16x8 qf[2][4];
#pragma unroll
  for (int qb = 0; qb < 2; ++qb)
#pragma unroll
    for (int kk = 0; kk < 4; ++kk)
      qf[qb][kk] = *(const s16x8*)(qkv + (size_t)(qrow0 + qb * 16 + opr) * QKVN +
                                   h * HD + kk * 32 + ak);

  float m_run[2] = {-1e30f, -1e30f};
  float l_run[2] = {0.f, 0.f};
  fx4 acc[8][2] = {};
  const float scale = 0.08838834764831845f;  // 1/sqrt(128)

  for (int t0 = 0; t0 < S_LEN; t0 += 64) {
    __syncthreads();  // prev tile's LDS reads complete
    const size_t krow0 = (size_t)(b * S_LEN + t0);
#pragma unroll
    for (int i = 0; i < 4; ++i) {  // K tile [64][128]
      int d = i * 4096 + tid * 16;
      int row = d >> 8;
      int colb = (d & 255) ^ ((row & 7) << 4);
      GLDS16(qkv + (krow0 + row) * QKVN + DMODEL + kvi * HD + (colb >> 1), (char*)Ks + d);
    }
#pragma unroll
    for (int i = 0; i < 4; ++i) {  // V^T tile [128][64]
      int d = i * 4096 + tid * 16;
      int row = d >> 7;
      int colb = (d & 127) ^ ((row & 7) << 4);
      GLDS16(vtb + (size_t)(kvi * HD + row) * MROWS + (size_t)(b * S_LEN + t0) + (colb >> 1),
             (char*)Vts + d);
    }
    __syncthreads();  // staged data visible (barrier drains vmcnt)

    // ---- S^T[key][q] = MFMA(K-frag, Q-frag) over d=128 ----
    fx4 st[4][2] = {};
#pragma unroll
    for (int kb2 = 0; kb2 < 4; ++kb2) {
      int krow = kb2 * 16 + opr;
      const char* kbase = (const char*)Ks + krow * 256;
      s16x8 kf[4];
#pragma unroll
      for (int kk = 0; kk < 4; ++kk)
        kf[kk] = *(const s16x8*)(kbase + ((kk * 64 + opk2) ^ ((krow & 7) << 4)));
#pragma unroll
      for (int qb = 0; qb < 2; ++qb)
#pragma unroll
        for (int kk = 0; kk < 4; ++kk)
          st[kb2][qb] = MFMA16(kf[kk], qf[qb][kk], st[kb2][qb]);
    }

    // ---- softmax per q-column ----
    float mloc[2], alpha[2], psum[2];
#pragma unroll
    for (int qb = 0; qb < 2; ++qb) {
      float mm = -1e30f;
#pragma unroll
      for (int kb2 = 0; kb2 < 4; ++kb2)
#pragma unroll
        for (int r = 0; r < 4; ++r) mm = fmaxf(mm, st[kb2][qb][r] * scale);
      mm = fmaxf(mm, __shfl_xor(mm, 16));
      mm = fmaxf(mm, __shfl_xor(mm, 32));
      mloc[qb] = mm;
      float mnew = fmaxf(m_run[qb], mm);
      alpha[qb] = __expf(m_run[qb] - mnew);   // first tile: exp(-huge) = 0
      m_run[qb] = mnew;
      psum[qb] = 0.f;
    }
#pragma unroll
    for (int db = 0; db < 8; ++db)
#pragma unroll
      for (int qb = 0; qb < 2; ++qb)
#pragma unroll
        for (int r = 0; r < 4; ++r) acc[db][qb][r] *= alpha[qb];

    // ---- p = exp(s-m); psum; packed P store (8x ds_write_b64, bit-identical) ----
#pragma unroll
    for (int kb2 = 0; kb2 < 4; ++kb2)
#pragma unroll
      for (int qb = 0; qb < 2; ++qb) {
        ushort4 o;
        float pv0 = __expf(st[kb2][qb][0] * scale - m_run[qb]);
        float pv1 = __expf(st[kb2][qb][1] * scale - m_run[qb]);
        float pv2 = __expf(st[kb2][qb][2] * scale - m_run[qb]);
        float pv3 = __expf(st[kb2][qb][3] * scale - m_run[qb]);
        psum[qb] += pv0 + pv1 + pv2 + pv3;
        o.x = f2bf(pv0); o.y = f2bf(pv1); o.z = f2bf(pv2); o.w = f2bf(pv3);
        *(ushort4*)&Pw[(qb * 16 + cn) * 72 + kb2 * 16 + cm] = o;
      }
#pragma unroll
    for (int qb = 0; qb < 2; ++qb) {
      float s = psum[qb];
      s += __shfl_xor(s, 16);
      s += __shfl_xor(s, 32);
      l_run[qb] = l_run[qb] * alpha[qb] + s;
    }

    // ---- P b-frags (wave-private LDS, in-order within wave) ----
    s16x8 pf[2][2];
#pragma unroll
    for (int qb = 0; qb < 2; ++qb)
#pragma unroll
      for (int tb = 0; tb < 2; ++tb)
        pf[qb][tb] = *(const s16x8*)(Pw + (qb * 16 + opr) * 72 + tb * 32 + ak);

    // ---- O^T += MFMA(V^T-frag, P-frag) over t=64 ----
#pragma unroll
    for (int db = 0; db < 8; ++db) {
      int vrow = db * 16 + opr;
      const char* vbase = (const char*)Vts + vrow * 128;
      s16x8 vf[2];
#pragma unroll
      for (int tb = 0; tb < 2; ++tb)
        vf[tb] = *(const s16x8*)(vbase + ((tb * 64 + opk2) ^ ((vrow & 7) << 4)));
#pragma unroll
      for (int qb = 0; qb < 2; ++qb)
#pragma unroll
        for (int tb = 0; tb < 2; ++tb)
          acc[db][qb] = MFMA16(vf[tb], pf[qb][tb], acc[db][qb]);
    }
  }

  // ---- epilogue: normalize per q, pack 4 consecutive d -> 8B ----
  float inv[2] = {1.0f / l_run[0], 1.0f / l_run[1]};
#pragma unroll
  for (int db = 0; db < 8; ++db)
#pragma unroll
    for (int qb = 0; qb < 2; ++qb) {
      ushort4 o;
      o.x = f2bf(acc[db][qb][0] * inv[qb]);
      o.y = f2bf(acc[db][qb][1] * inv[qb]);
      o.z = f2bf(acc[db][qb][2] * inv[qb]);
      o.w = f2bf(acc[db][qb][3] * inv[qb]);
      *(ushort4*)(aob + (size_t)(qrow0 + qb * 16 + cn) * DMODEL + h * HD + db * 16 + cm) = o;
    }
}

// ---------------- launch ----------------
extern "C" void kernel_launch(void* const* d_in, const int* in_sizes, int n_in,
                              void* d_out, int out_size, void* d_ws, size_t ws_size,
                              hipStream_t stream) {
  const float* hs = (const float*)d_in[0];
  const float* fr = (const float*)d_in[1];
  const float* Wq = (const float*)d_in[2];
  const float* Wk = (const float*)d_in[3];
  const float* Wv = (const float*)d_in[4];
  const float* Wo = (const float*)d_in[5];
  const int* pos = (const int*)d_in[6];
  float* out = (float*)d_out;

  // workspace (bf16 elems), total 83,886,080 shorts = 167.8 MB
  unsigned short* w = (unsigned short*)d_ws;
  unsigned short* hsb   = w; w += 16777216;  // [4096,4096] hs bf16
  unsigned short* wqkvb = w; w += 25165824;  // [6144,4096] Wq|Wk|Wv  (aob+vtb reuse after gemm)
  unsigned short* wob   = w; w += 16777216;  // [4096,4096]
  unsigned short* qkvb  = w; w += 25165824;  // [4096,6144] q|k|v per row
  unsigned short* aob = wqkvb;               // [4096,4096] attn out
  unsigned short* vtb = wqkvb + 16777216;    // [1024,4096] V^T
  float2* tab = (float2*)out;                // cos/sin table in d_out (dead until O-gemm,
                                             // which overwrites every element)

  if (ws_size < (size_t)83886080 * 2) return;

  cast_all_k<<<28672, 256, 0, stream>>>(hs, Wq, Wk, Wv, Wo, hsb, wqkvb, wob);
  rope_tab_k<<<512, 256, 0, stream>>>(fr, pos, tab);

  // Q projection + fused rope: grid 256 = 1 clean round -> qkvb cols 0..4095
  gemm256<<<256, 512, 0, stream>>>(hsb, wqkvb, nullptr, qkvb, tab,
                                   MROWS, DMODEL, DMODEL, QKVN, 1, 1);
  // KV projection + fused rope on K tiles (tn<4): grid 128 -> qkvb cols 4096..6143
  gemm256<<<128, 512, 0, stream>>>(hsb, wqkvb + (size_t)DMODEL * DMODEL, nullptr,
                                   qkvb + DMODEL, tab, MROWS, 2048, DMODEL, QKVN, 2, 1);

  transpose_k<<<1024, 256, 0, stream>>>(qkvb + 5120, vtb, MROWS, 1024, QKVN);  // V -> V^T

  attn_mfma<<<1024, 256, 0, stream>>>(qkvb, vtb, aob);

  // output projection: grid 256 clean -> f32 out (overwrites tab region fully)
  gemm256<<<256, 512, 0, stream>>>(aob, wob, out, nullptr, nullptr,
                                   MROWS, DMODEL, DMODEL, DMODEL, 0, 0);
}

// Round 16
// 611.799 us; speedup vs baseline: 1.0768x; 1.0768x over previous
//
#include <hip/hip_runtime.h>

// ---------------- constants ----------------
#define S_LEN 2048
#define NH 32
#define NKV 8
#define HD 128
#define DMODEL 4096
#define MROWS 4096   // B*S
#define QKVN 6144    // 4096 q + 1024 k + 1024 v output cols

typedef short s16x8 __attribute__((ext_vector_type(8)));
typedef float fx4 __attribute__((ext_vector_type(4)));

__device__ __forceinline__ unsigned short f2bf(float f) {
  unsigned int u = __float_as_uint(f);
  u += 0x7fffu + ((u >> 16) & 1u);   // round-to-nearest-even
  return (unsigned short)(u >> 16);
}
__device__ __forceinline__ float bf2f(unsigned short h) {
  return __uint_as_float(((unsigned int)h) << 16);
}

#define GLDS16(gp, lp)                                                        \
  __builtin_amdgcn_global_load_lds(                                           \
      (const __attribute__((address_space(1))) void*)(gp),                    \
      (__attribute__((address_space(3))) void*)(lp), 16, 0, 0)

#define MFMA16(a, b, c) __builtin_amdgcn_mfma_f32_16x16x32_bf16((a), (b), (c), 0, 0, 0)

// ---------------- fused f32 -> bf16 casts, 8 floats/thread (R13-verified) ----------------
__global__ __launch_bounds__(256) void cast_all_k(const float* __restrict__ hs,
                                                  const float* __restrict__ Wq,
                                                  const float* __restrict__ Wk,
                                                  const float* __restrict__ Wv,
                                                  const float* __restrict__ Wo,
                                                  unsigned short* __restrict__ hsb,
                                                  unsigned short* __restrict__ wqkvb,
                                                  unsigned short* __restrict__ wob) {
  int i = blockIdx.x * 256 + threadIdx.x;   // float8 index
  const float* src;
  unsigned short* dst;
  int off;
  if (i < 2097152)      { src = hs; dst = hsb;               off = 0; }
  else if (i < 4194304) { src = Wq; dst = wqkvb;             off = 2097152; }
  else if (i < 4718592) { src = Wk; dst = wqkvb + 16777216;  off = 4194304; }
  else if (i < 5242880) { src = Wv; dst = wqkvb + 20971520;  off = 4718592; }
  else                  { src = Wo; dst = wob;               off = 5242880; }
  int j = i - off;
  float4 v0 = *(const float4*)(src + (size_t)j * 8);
  float4 v1 = *(const float4*)(src + (size_t)j * 8 + 4);
  s16x8 o;
  o[0] = (short)f2bf(v0.x); o[1] = (short)f2bf(v0.y);
  o[2] = (short)f2bf(v0.z); o[3] = (short)f2bf(v0.w);
  o[4] = (short)f2bf(v1.x); o[5] = (short)f2bf(v1.y);
  o[6] = (short)f2bf(v1.z); o[7] = (short)f2bf(v1.w);
  *(s16x8*)(dst + (size_t)j * 8) = o;
}

// ---------------- 256x256 8-phase bf16 GEMM (R7-verified) + ldc (R12/R13-verified) ----------------
__global__ __launch_bounds__(512, 2) void gemm256(const unsigned short* __restrict__ A,
                                                  const unsigned short* __restrict__ Bt,
                                                  float* __restrict__ Cf,
                                                  unsigned short* __restrict__ Cb,
                                                  int M, int N, int K, int ldc, int bf16out) {
  __shared__ unsigned short Abuf[2][16384];  // [2][256 rows][64 cols]
  __shared__ unsigned short Bbuf[2][16384];
  const int tid = threadIdx.x;
  const int lane = tid & 63;
  const int w = tid >> 6;
  const int wm = w >> 2;   // 0..1
  const int wn = w & 3;    // 0..3

  const int nm = M >> 8;
  const int nn = N >> 8;
  const int rh = nm >> 1;              // rectangle height (tiles)
  const int rw = nn >> 2;              // rectangle width (tiles)
  const int xcd = blockIdx.x & 7;
  const int l = blockIdx.x >> 3;       // per-XCD sequence
  const int tm = (xcd >> 2) * rh + (l % rh);
  const int tn = (xcd & 3) * rw + (l / rh);

  const int opr = lane & 15;
  const int opk2 = (lane >> 4) << 4;   // byte offset {0,16,32,48}
  const int NT = K >> 6;

  const unsigned short* Agbase = A + (size_t)(tm * 256) * K;
  const unsigned short* Bgbase = Bt + (size_t)(tn * 256) * K;
  const int abase = wm * 16384 + wn * 4096;
  const int bbase = (wn >> 1) * 16384 + (wm * 2 + (wn & 1)) * 4096;

  auto stageA = [&](int bsel, int kt) {
#pragma unroll
    for (int r = 0; r < 4; ++r) {
      const int d = abase + r * 1024 + lane * 16;
      const int row = d >> 7;
      const int u = (d & 127) ^ ((row & 7) << 4);
      GLDS16(Agbase + (size_t)row * K + kt * 64 + (u >> 1), (char*)&Abuf[bsel][0] + d);
    }
  };
  auto stageB = [&](int bsel, int kt) {
#pragma unroll
    for (int r = 0; r < 4; ++r) {
      const int d = bbase + r * 1024 + lane * 16;
      const int row = d >> 7;
      const int u = (d & 127) ^ ((row & 7) << 4);
      GLDS16(Bgbase + (size_t)row * K + kt * 64 + (u >> 1), (char*)&Bbuf[bsel][0] + d);
    }
  };

  fx4 acc[8][4] = {};

  stageA(0, 0); stageB(0, 0);
  stageA(1, 1); stageB(1, 1);
  asm volatile("s_waitcnt vmcnt(8)" ::: "memory");
  __builtin_amdgcn_s_barrier();

#define PH_SYNC()                                            \
  do {                                                       \
    __builtin_amdgcn_s_barrier();                            \
    asm volatile("s_waitcnt lgkmcnt(0)" ::: "memory");       \
    __builtin_amdgcn_sched_barrier(0);                       \
  } while (0)

#pragma unroll 1
  for (int t = 0; t < NT; ++t) {
    const int cur = t & 1;
    const unsigned short* Abc = Abuf[cur];
    const unsigned short* Bbc = Bbuf[cur];
    const int kt2 = (t + 2) & (NT - 1);
    s16x8 a0[8], a1[8], b0[4], b1[4];

#pragma unroll
    for (int i = 0; i < 8; ++i) {
      const int row = wm * 128 + i * 16 + opr;
      a0[i] = *(const s16x8*)((const char*)Abc + row * 128 + (opk2 ^ ((row & 7) << 4)));
    }
#pragma unroll
    for (int j = 0; j < 4; ++j) {
      const int row = wn * 64 + j * 16 + opr;
      b0[j] = *(const s16x8*)((const char*)Bbc + row * 128 + (opk2 ^ ((row & 7) << 4)));
    }
    PH_SYNC();
    __builtin_amdgcn_s_setprio(1);
#pragma unroll
    for (int i = 0; i < 4; ++i)
#pragma unroll
      for (int j = 0; j < 4; ++j) acc[i][j] = MFMA16(a0[i], b0[j], acc[i][j]);
    __builtin_amdgcn_s_setprio(0);
    __builtin_amdgcn_s_barrier();

#pragma unroll
    for (int i = 0; i < 8; ++i) {
      const int row = wm * 128 + i * 16 + opr;
      a1[i] = *(const s16x8*)((const char*)Abc + row * 128 + ((64 + opk2) ^ ((row & 7) << 4)));
    }
    PH_SYNC();
    __builtin_amdgcn_s_setprio(1);
#pragma unroll
    for (int i = 4; i < 8; ++i)
#pragma unroll
      for (int j = 0; j < 4; ++j) acc[i][j] = MFMA16(a0[i], b0[j], acc[i][j]);
    __builtin_amdgcn_s_setprio(0);
    __builtin_amdgcn_s_barrier();

#pragma unroll
    for (int j = 0; j < 4; ++j) {
      const int row = wn * 64 + j * 16 + opr;
      b1[j] = *(const s16x8*)((const char*)Bbc + row * 128 + ((64 + opk2) ^ ((row & 7) << 4)));
    }
    stageA(cur, kt2);
    PH_SYNC();
    __builtin_amdgcn_s_setprio(1);
#pragma unroll
    for (int i = 0; i < 4; ++i)
#pragma unroll
      for (int j = 0; j < 4; ++j) acc[i][j] = MFMA16(a1[i], b1[j], acc[i][j]);
    __builtin_amdgcn_s_setprio(0);
    __builtin_amdgcn_s_barrier();

    stageB(cur, kt2);
    __builtin_amdgcn_s_barrier();
    __builtin_amdgcn_s_setprio(1);
#pragma unroll
    for (int i = 4; i < 8; ++i)
#pragma unroll
      for (int j = 0; j < 4; ++j) acc[i][j] = MFMA16(a1[i], b1[j], acc[i][j]);
    __builtin_amdgcn_s_setprio(0);
    asm volatile("s_waitcnt vmcnt(8)" ::: "memory");
    __builtin_amdgcn_s_barrier();
  }
#undef PH_SYNC

  const int cm = (lane >> 4) << 2;
  const int cn = lane & 15;
#pragma unroll
  for (int i = 0; i < 8; ++i)
#pragma unroll
    for (int j = 0; j < 4; ++j) {
      const int row = tm * 256 + wm * 128 + i * 16 + cm;
      const int col = tn * 256 + wn * 64 + j * 16 + cn;
#pragma unroll
      for (int r = 0; r < 4; ++r) {
        float v = acc[i][j][r];
        if (bf16out) Cb[(size_t)(row + r) * ldc + col] = f2bf(v);
        else         Cf[(size_t)(row + r) * ldc + col] = v;
      }
    }
}

// ---------------- bf16 transpose: out[C][R] = in[R][C]^T (in rows strided) ----------------
__global__ __launch_bounds__(256) void transpose_k(const unsigned short* __restrict__ in,
                                                   unsigned short* __restrict__ out,
                                                   int R, int C, int istride) {
  __shared__ unsigned short T[64][68];
  const int tid = threadIdx.x;
  const int nbc = C >> 6;
  const int br = blockIdx.x / nbc;
  const int bc = blockIdx.x % nbc;
  const int r0 = br << 6, c0 = bc << 6;
#pragma unroll
  for (int i = 0; i < 4; ++i) {
    int row = i * 16 + (tid >> 4);
    int col = (tid & 15) << 2;
    *(ushort4*)&T[row][col] = *(const ushort4*)(in + (size_t)(r0 + row) * istride + c0 + col);
  }
  __syncthreads();
#pragma unroll
  for (int i = 0; i < 4; ++i) {
    int row = i * 16 + (tid >> 4);
    int col = (tid & 15) << 2;
    ushort4 v;
    v.x = T[col + 0][row]; v.y = T[col + 1][row];
    v.z = T[col + 2][row]; v.w = T[col + 3][row];
    *(ushort4*)(out + (size_t)(c0 + row) * R + r0 + col) = v;
  }
}

// ---------------- RoPE apply, in-place on merged qkv buffer (inline sincos; R13) ----------------
__global__ __launch_bounds__(256) void rope_k(unsigned short* __restrict__ qkv,
                                              const float* __restrict__ freqs,
                                              const int* __restrict__ pos) {
  int idx = blockIdx.x * 256 + threadIdx.x;  // 4096 * 40 * 64
  int d2 = idx & 63;
  int t = idx >> 6;
  int hh = t % (NH + NKV);
  int row = t / (NH + NKV);
  int s = row & (S_LEN - 1);
  float ang = freqs[((size_t)(pos[0] + s) << 6) + d2];
  float sv, cv;
  sincosf(ang, &sv, &cv);
  unsigned short* p = qkv + (size_t)row * QKVN +
                      (hh < NH ? hh * HD : DMODEL + (hh - NH) * HD) + (d2 << 1);
  unsigned int xy = *(unsigned int*)p;
  float x1 = bf2f((unsigned short)(xy & 0xffffu));
  float x2 = bf2f((unsigned short)(xy >> 16));
  float o1 = x1 * cv - x2 * sv;
  float o2 = x1 * sv + x2 * cv;
  *(unsigned int*)p = (unsigned int)f2bf(o1) | ((unsigned int)f2bf(o2) << 16);
}

// ---------------- MFMA flash attention — R13 geometry + T13 defer-rescale softmax ----------------
// R16 changes vs R13 (softmax VALU diet, math exact):
//  - fmax chain over RAW st (scale>0 preserves order); one mult at the end.
//  - exp via fmaf(st, scale, -m_run) — no separate scale pass.
//  - T13 defer-rescale THR=8: acc/l rescale only when __any(mloc > m_run+8)
//    (wave-uniform). P bounded by e^8 (fits bf16); l sums the same shifted
//    exps -> exact. First tile always rescales (m_run=-1e30, alpha=0).
//  - packed P-store (8x ds_write_b64, bit-identical values; from R15, neutral).
__global__ __launch_bounds__(256, 2) void attn_mfma(const unsigned short* __restrict__ qkv,
                                                    const unsigned short* __restrict__ vtb,
                                                    unsigned short* __restrict__ aob) {
  __shared__ alignas(16) unsigned short Ks[64 * 128];    // 16 KB (swizzled)
  __shared__ alignas(16) unsigned short Vts[128 * 64];   // 16 KB (swizzled)
  __shared__ alignas(16) unsigned short Ps[4][32 * 72];  // 18 KB
  const int tid = threadIdx.x;
  const int lane = tid & 63;
  const int w = tid >> 6;
  const int lg = (blockIdx.x & 7) * 128 + (blockIdx.x >> 3);  // grid = 1024
  const int qc = lg & 15;            // 16 q-chunks of 128 rows
  const int hsub = (lg >> 4) & 3;
  const int kvi = (lg >> 6) & 7;
  const int b = lg >> 9;
  const int h = kvi * 4 + hsub;

  const int opr = lane & 15;         // operand row within 16
  const int g = lane >> 4;           // k-subblock 0..3
  const int ak = g * 8;              // operand k offset (shorts)
  const int opk2 = g * 16;           // operand k offset (bytes)
  const int cm = g * 4;              // C/D row base
  const int cn = opr;                // C/D col

  const int qrow0 = b * S_LEN + qc * 128 + w * 32;
  unsigned short* Pw = Ps[w];

  // ---- Q b-frags hoisted once from global ----
  s16x8 qf[2][4];
#pragma unroll
  for (int qb = 0; qb < 2; ++qb)
#pragma unroll
    for (int kk = 0; kk < 4; ++kk)
      qf[qb][kk] = *(const s16x8*)(qkv + (size_t)(qrow0 + qb * 16 + opr) * QKVN +
                                   h * HD + kk * 32 + ak);

  float m_run[2] = {-1e30f, -1e30f};
  float l_run[2] = {0.f, 0.f};
  fx4 acc[8][2] = {};
  const float scale = 0.08838834764831845f;  // 1/sqrt(128)

  for (int t0 = 0; t0 < S_LEN; t0 += 64) {
    __syncthreads();  // prev tile's LDS reads complete
    const size_t krow0 = (size_t)(b * S_LEN + t0);
#pragma unroll
    for (int i = 0; i < 4; ++i) {  // K tile [64][128]
      int d = i * 4096 + tid * 16;
      int row = d >> 8;
      int colb = (d & 255) ^ ((row & 7) << 4);
      GLDS16(qkv + (krow0 + row) * QKVN + DMODEL + kvi * HD + (colb >> 1), (char*)Ks + d);
    }
#pragma unroll
    for (int i = 0; i < 4; ++i) {  // V^T tile [128][64]
      int d = i * 4096 + tid * 16;
      int row = d >> 7;
      int colb = (d & 127) ^ ((row & 7) << 4);
      GLDS16(vtb + (size_t)(kvi * HD + row) * MROWS + (size_t)(b * S_LEN + t0) + (colb >> 1),
             (char*)Vts + d);
    }
    __syncthreads();  // staged data visible (barrier drains vmcnt)

    // ---- S^T[key][q] = MFMA(K-frag, Q-frag) over d=128 ----
    fx4 st[4][2] = {};
#pragma unroll
    for (int kb2 = 0; kb2 < 4; ++kb2) {
      int krow = kb2 * 16 + opr;
      const char* kbase = (const char*)Ks + krow * 256;
      s16x8 kf[4];
#pragma unroll
      for (int kk = 0; kk < 4; ++kk)
        kf[kk] = *(const s16x8*)(kbase + ((kk * 64 + opk2) ^ ((krow & 7) << 4)));
#pragma unroll
      for (int qb = 0; qb < 2; ++qb)
#pragma unroll
        for (int kk = 0; kk < 4; ++kk)
          st[kb2][qb] = MFMA16(kf[kk], qf[qb][kk], st[kb2][qb]);
    }

    // ---- per-q-column tile max (raw domain; scale folded at the end) ----
    float mloc[2];
#pragma unroll
    for (int qb = 0; qb < 2; ++qb) {
      float mm = -1e30f;
#pragma unroll
      for (int kb2 = 0; kb2 < 4; ++kb2)
#pragma unroll
        for (int r = 0; r < 4; ++r) mm = fmaxf(mm, st[kb2][qb][r]);
      mm = fmaxf(mm, __shfl_xor(mm, 16));
      mm = fmaxf(mm, __shfl_xor(mm, 32));
      mloc[qb] = mm * scale;
    }

    // ---- T13 defer-rescale: only when some column's max grew past THR=8 ----
    if (__any((mloc[0] > m_run[0] + 8.f) || (mloc[1] > m_run[1] + 8.f))) {
#pragma unroll
      for (int qb = 0; qb < 2; ++qb) {
        float mnew = fmaxf(m_run[qb], mloc[qb]);
        float alpha = __expf(m_run[qb] - mnew);  // first tile: exp(-huge) = 0
        m_run[qb] = mnew;
        l_run[qb] *= alpha;
#pragma unroll
        for (int db = 0; db < 8; ++db)
#pragma unroll
          for (int r = 0; r < 4; ++r) acc[db][qb][r] *= alpha;
      }
    }

    // ---- p = exp(st*scale - m) via fmaf; psum; packed P store ----
    float psum[2] = {0.f, 0.f};
#pragma unroll
    for (int kb2 = 0; kb2 < 4; ++kb2)
#pragma unroll
      for (int qb = 0; qb < 2; ++qb) {
        ushort4 o;
        float pv0 = __expf(fmaf(st[kb2][qb][0], scale, -m_run[qb]));
        float pv1 = __expf(fmaf(st[kb2][qb][1], scale, -m_run[qb]));
        float pv2 = __expf(fmaf(st[kb2][qb][2], scale, -m_run[qb]));
        float pv3 = __expf(fmaf(st[kb2][qb][3], scale, -m_run[qb]));
        psum[qb] += pv0 + pv1 + pv2 + pv3;
        o.x = f2bf(pv0); o.y = f2bf(pv1); o.z = f2bf(pv2); o.w = f2bf(pv3);
        *(ushort4*)&Pw[(qb * 16 + cn) * 72 + kb2 * 16 + cm] = o;
      }
#pragma unroll
    for (int qb = 0; qb < 2; ++qb) {
      float s = psum[qb];
      s += __shfl_xor(s, 16);
      s += __shfl_xor(s, 32);
      l_run[qb] += s;
    }

    // ---- P b-frags (wave-private LDS, in-order within wave) ----
    s16x8 pf[2][2];
#pragma unroll
    for (int qb = 0; qb < 2; ++qb)
#pragma unroll
      for (int tb = 0; tb < 2; ++tb)
        pf[qb][tb] = *(const s16x8*)(Pw + (qb * 16 + opr) * 72 + tb * 32 + ak);

    // ---- O^T += MFMA(V^T-frag, P-frag) over t=64 ----
#pragma unroll
    for (int db = 0; db < 8; ++db) {
      int vrow = db * 16 + opr;
      const char* vbase = (const char*)Vts + vrow * 128;
      s16x8 vf[2];
#pragma unroll
      for (int tb = 0; tb < 2; ++tb)
        vf[tb] = *(const s16x8*)(vbase + ((tb * 64 + opk2) ^ ((vrow & 7) << 4)));
#pragma unroll
      for (int qb = 0; qb < 2; ++qb)
#pragma unroll
        for (int tb = 0; tb < 2; ++tb)
          acc[db][qb] = MFMA16(vf[tb], pf[qb][tb], acc[db][qb]);
    }
  }

  // ---- epilogue: normalize per q, pack 4 consecutive d -> 8B ----
  float inv[2] = {1.0f / l_run[0], 1.0f / l_run[1]};
#pragma unroll
  for (int db = 0; db < 8; ++db)
#pragma unroll
    for (int qb = 0; qb < 2; ++qb) {
      ushort4 o;
      o.x = f2bf(acc[db][qb][0] * inv[qb]);
      o.y = f2bf(acc[db][qb][1] * inv[qb]);
      o.z = f2bf(acc[db][qb][2] * inv[qb]);
      o.w = f2bf(acc[db][qb][3] * inv[qb]);
      *(ushort4*)(aob + (size_t)(qrow0 + qb * 16 + cn) * DMODEL + h * HD + db * 16 + cm) = o;
    }
}

// ---------------- launch ----------------
extern "C" void kernel_launch(void* const* d_in, const int* in_sizes, int n_in,
                              void* d_out, int out_size, void* d_ws, size_t ws_size,
                              hipStream_t stream) {
  const float* hs = (const float*)d_in[0];
  const float* fr = (const float*)d_in[1];
  const float* Wq = (const float*)d_in[2];
  const float* Wk = (const float*)d_in[3];
  const float* Wv = (const float*)d_in[4];
  const float* Wo = (const float*)d_in[5];
  const int* pos = (const int*)d_in[6];
  float* out = (float*)d_out;

  // workspace (bf16 elems), total 83,886,080 shorts = 167.8 MB
  unsigned short* w = (unsigned short*)d_ws;
  unsigned short* hsb   = w; w += 16777216;  // [4096,4096] hs bf16
  unsigned short* wqkvb = w; w += 25165824;  // [6144,4096] Wq|Wk|Wv  (aob+vtb reuse after gemm)
  unsigned short* wob   = w; w += 16777216;  // [4096,4096]
  unsigned short* qkvb  = w; w += 25165824;  // [4096,6144] q|k|v per row (rope in-place)
  unsigned short* aob = wqkvb;               // [4096,4096] attn out
  unsigned short* vtb = wqkvb + 16777216;    // [1024,4096] V^T

  if (ws_size < (size_t)83886080 * 2) return;

  cast_all_k<<<28672, 256, 0, stream>>>(hs, Wq, Wk, Wv, Wo, hsb, wqkvb, wob);

  // Q projection: grid 256 = 1 clean round -> qkvb cols 0..4095
  gemm256<<<256, 512, 0, stream>>>(hsb, wqkvb, nullptr, qkvb, MROWS, DMODEL, DMODEL, QKVN, 1);
  // KV projection: grid 128 -> qkvb cols 4096..6143
  gemm256<<<128, 512, 0, stream>>>(hsb, wqkvb + (size_t)DMODEL * DMODEL, nullptr,
                                   qkvb + DMODEL, MROWS, 2048, DMODEL, QKVN, 1);

  rope_k<<<40960, 256, 0, stream>>>(qkvb, fr, pos);

  transpose_k<<<1024, 256, 0, stream>>>(qkvb + 5120, vtb, MROWS, 1024, QKVN);  // V -> V^T

  attn_mfma<<<1024, 256, 0, stream>>>(qkvb, vtb, aob);

  // output projection: grid 256 clean -> f32 out
  gemm256<<<256, 512, 0, stream>>>(aob, wob, out, nullptr, MROWS, DMODEL, DMODEL, DMODEL, 0);
}